// Round 6
// baseline (244.918 us; speedup 1.0000x reference)
//
#include <hip/hip_runtime.h>
#include <hip/hip_bf16.h>

// MHA: B=2, S=2048, D=1024, H=16, hd=64, fp32 in/out.
// Round 6: software pipelining (double-buffered LDS + post-barrier prefetch)
//          for all MFMA kernels; LDS union in gemm_qkv (48->32 KB).

constexpr int D_MODEL = 1024;
constexpr int S_LEN   = 2048;
constexpr int BATCH   = 2;
constexpr int NH      = 16;
constexpr int HD      = 64;
constexpr int ROWS    = BATCH * S_LEN;  // 4096

typedef __attribute__((ext_vector_type(8))) short short8;
typedef __attribute__((ext_vector_type(4))) float float4a;

static __device__ __forceinline__ unsigned short f2bf(float f) {
  union { float f; unsigned u; } v{f};
  unsigned r = v.u + 0x7FFFu + ((v.u >> 16) & 1u);  // RNE
  return (unsigned short)(r >> 16);
}

static __device__ __forceinline__ unsigned pack_bf16(float a, float b) {
#if __has_builtin(__builtin_amdgcn_cvt_pk_bf16_f32)
  typedef __attribute__((ext_vector_type(2))) __bf16 bf16x2;
  union { bf16x2 v; unsigned u; } c;
  c.v = __builtin_amdgcn_cvt_pk_bf16_f32(a, b);
  return c.u;
#else
  return (unsigned)f2bf(a) | ((unsigned)f2bf(b) << 16);
#endif
}

static __device__ __forceinline__ float bf2f(unsigned short u) {
  union { unsigned u; float f; } v;
  v.u = (unsigned)u << 16;
  return v.f;
}

// async 16B/lane global -> LDS (per-lane global addr, wave-uniform LDS base)
static __device__ __forceinline__ void async16(const void* g, void* l) {
  __builtin_amdgcn_global_load_lds(
      (const __attribute__((address_space(1))) unsigned int*)g,
      (__attribute__((address_space(3))) unsigned int*)l, 16, 0, 0);
}

// ---------------- fp32 -> bf16 convert ----------------
struct ConvArgs { const float* s[7]; unsigned short* d[7]; int n[7]; };

__global__ __launch_bounds__(256) void convert_bf16(ConvArgs a) {
  const int which = blockIdx.y;
  const int i = (blockIdx.x * 256 + threadIdx.x) * 8;
  if (i >= a.n[which]) return;
  const float4* s = (const float4*)(a.s[which] + i);
  float4 x = s[0], y = s[1];
  unsigned t[4] = {pack_bf16(x.x, x.y), pack_bf16(x.z, x.w),
                   pack_bf16(y.x, y.y), pack_bf16(y.z, y.w)};
  *(short8*)(a.d[which] + i) = *(short8*)t;
}

// ---------------- MFMA bf16 GEMM: Y = A @ W^T (+bias) ----------------
// BM x 128 block tile, BK=32, double-buffered DMA staging.
// LDS slot swizzle: slot(r,c) = r*4 + ((c + (r>>1)) & 3)  (16B chunks).
// MODE 0: bf16 head-major [B,H,S,64], value = (acc + bias)*scale
// MODE 2: bf16 V^T [B,H,64,S] (XOR-swizzled LDS transpose epilogue, aliased)
// MODE 3: fp32 row-major [ROWS, 1024]
template <int BM>
static __device__ __forceinline__ void gemm_stage(
    const unsigned short* A, const unsigned short* W, int row0, int col0,
    int w, int lane, unsigned short* As, unsigned short* Bs, int kt, int par) {
  unsigned short* Bd = Bs + par * (128 * 32);
#pragma unroll
  for (int j = 0; j < 2; j++) {
    const int i = w * 2 + j;
    const int r = i * 16 + (lane >> 2);
    const int c = ((lane & 3) - (r >> 1)) & 3;
    async16(W + (size_t)(col0 + r) * D_MODEL + kt + c * 8, (char*)Bd + i * 1024);
  }
  unsigned short* Ad = As + par * (BM * 32);
  if constexpr (BM == 128) {
#pragma unroll
    for (int j = 0; j < 2; j++) {
      const int i = w * 2 + j;
      const int r = i * 16 + (lane >> 2);
      const int c = ((lane & 3) - (r >> 1)) & 3;
      async16(A + (size_t)(row0 + r) * D_MODEL + kt + c * 8, (char*)Ad + i * 1024);
    }
  } else {
    const int r = w * 16 + (lane >> 2);
    const int c = ((lane & 3) - (r >> 1)) & 3;
    async16(A + (size_t)(row0 + r) * D_MODEL + kt + c * 8, (char*)Ad + w * 1024);
  }
}

template <int MODE, int BM>
static __device__ __forceinline__ void gemm_body(
    const unsigned short* __restrict__ A, const unsigned short* __restrict__ W,
    const float* __restrict__ bias, void* __restrict__ Yv, float scale,
    unsigned short* As, unsigned short* Bs, unsigned short* Tb) {
  constexpr int NT = (BM == 128) ? 4 : 2;
  constexpr int KI = D_MODEL / 32;  // 32 iterations
  const int tid = threadIdx.x;
  const int w = tid >> 6, lane = tid & 63;
  const int l15 = lane & 15, quad = lane >> 4;
  const int row0 = blockIdx.x * BM, col0 = blockIdx.y * 128;
  const int wm = (BM == 128) ? (w & 1) * 64 : 0;
  const int wn = (BM == 128) ? (w >> 1) * 64 : w * 32;

  float4a acc[4][NT];
#pragma unroll
  for (int i = 0; i < 4; i++)
#pragma unroll
    for (int j = 0; j < NT; j++) acc[i][j] = (float4a){0.f, 0.f, 0.f, 0.f};

  const int swA = (quad + (wm >> 1) + (l15 >> 1)) & 3;
  const int swB = (quad + (wn >> 1) + (l15 >> 1)) & 3;

  gemm_stage<BM>(A, W, row0, col0, w, lane, As, Bs, 0, 0);

  for (int it = 0; it < KI; ++it) {
    __syncthreads();  // drains DMA for buf[it&1]; all prior reads of buf[(it+1)&1] done
    if (it + 1 < KI)
      gemm_stage<BM>(A, W, row0, col0, w, lane, As, Bs, (it + 1) * 32, (it + 1) & 1);
    const int par = it & 1;
    const unsigned short* Ab = As + par * (BM * 32);
    const unsigned short* Bb = Bs + par * (128 * 32);

    short8 af[4], bf[NT];
#pragma unroll
    for (int mt = 0; mt < 4; mt++) {
      const int r = wm + mt * 16 + l15;
      af[mt] = *(const short8*)&Ab[(r * 4 + swA) * 8];
    }
#pragma unroll
    for (int nt = 0; nt < NT; nt++) {
      const int r = wn + nt * 16 + l15;
      bf[nt] = *(const short8*)&Bb[(r * 4 + swB) * 8];
    }
#pragma unroll
    for (int mt = 0; mt < 4; mt++)
#pragma unroll
      for (int nt = 0; nt < NT; nt++)
        acc[mt][nt] = __builtin_amdgcn_mfma_f32_16x16x32_bf16(af[mt], bf[nt], acc[mt][nt], 0, 0, 0);
  }

  int cols[NT];
  float bvs[NT];
#pragma unroll
  for (int nt = 0; nt < NT; nt++) {
    cols[nt] = col0 + wn + nt * 16 + l15;
    bvs[nt]  = bias[cols[nt]] * ((MODE == 0) ? scale : 1.0f);
  }

  if constexpr (MODE == 0) {
    unsigned short* Y = (unsigned short*)Yv;
#pragma unroll
    for (int mt = 0; mt < 4; mt++)
#pragma unroll
      for (int r = 0; r < 4; r++) {
        const int m = row0 + wm + mt * 16 + quad * 4 + r;
        const int bb = m >> 11, s = m & 2047;
#pragma unroll
        for (int nt = 0; nt < NT; nt++) {
          const int h = cols[nt] >> 6, d = cols[nt] & 63;
          Y[(((size_t)(bb * NH + h)) * S_LEN + s) * HD + d] =
              f2bf(acc[mt][nt][r] * scale + bvs[nt]);
        }
      }
  } else if constexpr (MODE == 2) {
    __syncthreads();  // Tb aliases staging buffers: all waves' K-loop reads done
    unsigned short* T = Tb + w * 64 * 64;
#pragma unroll
    for (int mt = 0; mt < 4; mt++)
#pragma unroll
      for (int r = 0; r < 4; r++) {
        const int sl = mt * 16 + quad * 4 + r;
        const int cch = sl >> 3;
#pragma unroll
        for (int nt = 0; nt < NT; nt++) {
          const int dl = cols[nt] - col0 - wn;
          const int slot = cch ^ (dl & 7);
          T[dl * 64 + slot * 8 + (sl & 7)] = f2bf(acc[mt][nt][r] + bvs[nt]);
        }
      }
    asm volatile("s_waitcnt lgkmcnt(0)" ::: "memory");  // per-wave T write->read
    unsigned short* Y = (unsigned short*)Yv;
#pragma unroll
    for (int j = 0; j < 8; j++) {
      const int cid = j * 64 + lane;
      const int dl = cid >> 3;
      const int c  = cid & 7;
      const int slot = c ^ (dl & 7);
      short8 v = *(const short8*)&T[dl * 64 + slot * 8];
      const int col = col0 + wn + dl;
      const int h = col >> 6, d = col & 63;
      const int m = row0 + wm + c * 8;
      const int bb = m >> 11, s = m & 2047;
      *(short8*)&Y[(((size_t)(bb * NH + h)) * HD + d) * S_LEN + s] = v;
    }
  } else {  // MODE 3
    float* Y = (float*)Yv;
#pragma unroll
    for (int mt = 0; mt < 4; mt++)
#pragma unroll
      for (int r = 0; r < 4; r++) {
        const int m = row0 + wm + mt * 16 + quad * 4 + r;
#pragma unroll
        for (int nt = 0; nt < NT; nt++)
          Y[(size_t)m * D_MODEL + cols[nt]] = acc[mt][nt][r] + bvs[nt];
      }
  }
}

__global__ __launch_bounds__(256) void gemm_qkv(
    const unsigned short* xq, const unsigned short* xk, const unsigned short* xv,
    const unsigned short* wq, const unsigned short* wk, const unsigned short* wv,
    const float* bq, const float* bk, const float* bv,
    unsigned short* Q, unsigned short* K, unsigned short* Vt) {
  __shared__ unsigned short smem[4 * 128 * 32];  // 32 KB: As(2 buf) + Bs(2 buf); Tb aliases all
  unsigned short* As = smem;
  unsigned short* Bs = smem + 2 * 128 * 32;
  unsigned short* Tb = smem;
  const int z = blockIdx.z;
  // Q scale: 1/sqrt(64) * log2(e)  (softmax in exp2 domain)
  if (z == 0)      gemm_body<0, 128>(xq, wq, bq, Q,  0.125f * 1.44269504f, As, Bs, Tb);
  else if (z == 1) gemm_body<0, 128>(xk, wk, bk, K,  1.0f, As, Bs, Tb);
  else             gemm_body<2, 128>(xv, wv, bv, Vt, 1.0f, As, Bs, Tb);
}

__global__ __launch_bounds__(256) void gemm_o(const unsigned short* o16, const unsigned short* wo,
                                              const float* bo, float* out) {
  __shared__ unsigned short As[2 * 64 * 32];
  __shared__ unsigned short Bs[2 * 128 * 32];
  gemm_body<3, 64>(o16, wo, bo, out, 1.0f, As, Bs, nullptr);
}

// ---------------- Flash attention, split-K x2, pipelined DMA ----------------
// grid (16, 16, 4): qb, h, z = bb*2 + split. Wave w owns 32 q rows.
// P = exp2(S^T) (Q pre-scaled by log2e/8). l accumulated by MFMA with ones.
// Un-normalized bf16 partial O + fp32 l per split; merged later.
__global__ __launch_bounds__(256) void attn_kernel(
    const unsigned short* __restrict__ Qh, const unsigned short* __restrict__ Kh,
    const unsigned short* __restrict__ Vt, unsigned short* __restrict__ Op,
    float* __restrict__ Lp) {
  const int qb = blockIdx.x;
  const int h  = blockIdx.y;
  const int bb = blockIdx.z >> 1, sp = blockIdx.z & 1;
  const int tid = threadIdx.x;
  const int w = tid >> 6, lane = tid & 63;
  const int l15 = lane & 15, quad = lane >> 4;

  __shared__ unsigned short Ks[2][64 * 64];  // slot(r,c)=r*8+((c+r)&7), 16B chunks
  __shared__ unsigned short Vs[2][64 * 64];
  __shared__ unsigned short Ps[4][32][72];

  const size_t bh = (size_t)(bb * NH + h);
  const unsigned short* Qp = Qh + bh * S_LEN * HD;
  const unsigned short* Kp = Kh + bh * S_LEN * HD;
  const unsigned short* Vp = Vt + bh * (size_t)HD * S_LEN;

  short8 qf[2][2];
#pragma unroll
  for (int qnt = 0; qnt < 2; qnt++)
#pragma unroll
    for (int c = 0; c < 2; c++)
      qf[qnt][c] = *(const short8*)(Qp + (size_t)(qb * 128 + w * 32 + qnt * 16 + l15) * HD +
                                    c * 32 + quad * 8);

  unsigned short ob[8] = {0x3F80, 0x3F80, 0x3F80, 0x3F80, 0x3F80, 0x3F80, 0x3F80, 0x3F80};
  const short8 ones = *(short8*)ob;

  float4a Oacc[2][4];
#pragma unroll
  for (int a = 0; a < 2; a++)
#pragma unroll
    for (int b = 0; b < 4; b++) Oacc[a][b] = (float4a){0.f, 0.f, 0.f, 0.f};
  float4a Lacc[2] = {(float4a){0.f, 0.f, 0.f, 0.f}, (float4a){0.f, 0.f, 0.f, 0.f}};

  const int sw0 = (quad + l15) & 7;
  const int sw1 = (quad + 4 + l15) & 7;

  auto stage = [&](int kb, int par) {
#pragma unroll
    for (int j = 0; j < 2; j++) {
      const int i = w * 2 + j;
      const int r = i * 8 + (lane >> 3);
      const int c = ((lane & 7) - r) & 7;
      async16(Kp + (size_t)(kb + r) * HD + c * 8, (char*)&Ks[par][0] + i * 1024);
      async16(Vp + (size_t)r * S_LEN + kb + c * 8, (char*)&Vs[par][0] + i * 1024);
    }
  };

  const int kb0 = sp * 1024;
  stage(kb0, 0);

  for (int t = 0; t < 16; ++t) {
    __syncthreads();  // drains DMA for buf[t&1]; prior reads of buf[(t+1)&1] done
    if (t + 1 < 16) stage(kb0 + (t + 1) * 64, (t + 1) & 1);
    const int par = t & 1;

    // S^T = K·Q^T, p = exp2(s) -> P (bf16) into per-wave LDS
#pragma unroll
    for (int mt = 0; mt < 4; mt++) {
      const int rb = (mt * 16 + l15) * 8;
      short8 a0 = *(const short8*)&Ks[par][(rb + sw0) * 8];
      short8 a1 = *(const short8*)&Ks[par][(rb + sw1) * 8];
#pragma unroll
      for (int qnt = 0; qnt < 2; qnt++) {
        float4a s = (float4a){0.f, 0.f, 0.f, 0.f};
        s = __builtin_amdgcn_mfma_f32_16x16x32_bf16(a0, qf[qnt][0], s, 0, 0, 0);
        s = __builtin_amdgcn_mfma_f32_16x16x32_bf16(a1, qf[qnt][1], s, 0, 0, 0);
        uint2 pk;
        pk.x = pack_bf16(__builtin_amdgcn_exp2f(s[0]), __builtin_amdgcn_exp2f(s[1]));
        pk.y = pack_bf16(__builtin_amdgcn_exp2f(s[2]), __builtin_amdgcn_exp2f(s[3]));
        *(uint2*)&Ps[w][qnt * 16 + l15][mt * 16 + quad * 4] = pk;
      }
    }
    asm volatile("s_waitcnt lgkmcnt(0)" ::: "memory");  // P write->read, same wave

    // O += P·V ; l += P·1 (MFMA)
#pragma unroll
    for (int c = 0; c < 2; c++) {
      short8 pa0 = *(const short8*)&Ps[w][l15][c * 32 + quad * 8];
      short8 pa1 = *(const short8*)&Ps[w][16 + l15][c * 32 + quad * 8];
      Lacc[0] = __builtin_amdgcn_mfma_f32_16x16x32_bf16(pa0, ones, Lacc[0], 0, 0, 0);
      Lacc[1] = __builtin_amdgcn_mfma_f32_16x16x32_bf16(pa1, ones, Lacc[1], 0, 0, 0);
      const int vsw = (c * 4 + quad + l15) & 7;
#pragma unroll
      for (int nt = 0; nt < 4; nt++) {
        short8 vb = *(const short8*)&Vs[par][((nt * 16 + l15) * 8 + vsw) * 8];
        Oacc[0][nt] = __builtin_amdgcn_mfma_f32_16x16x32_bf16(pa0, vb, Oacc[0][nt], 0, 0, 0);
        Oacc[1][nt] = __builtin_amdgcn_mfma_f32_16x16x32_bf16(pa1, vb, Oacc[1][nt], 0, 0, 0);
      }
    }
  }

  if (l15 == 0) {
#pragma unroll
    for (int qnt = 0; qnt < 2; qnt++)
#pragma unroll
      for (int reg = 0; reg < 4; reg++) {
        const int q = qb * 128 + w * 32 + qnt * 16 + quad * 4 + reg;
        Lp[(size_t)sp * ROWS * NH + ((size_t)bb * S_LEN + q) * NH + h] = Lacc[qnt][reg];
      }
  }

  unsigned short* Ob = Op + (size_t)sp * ROWS * D_MODEL;
#pragma unroll
  for (int qnt = 0; qnt < 2; qnt++) {
#pragma unroll
    for (int reg = 0; reg < 4; reg++) {
      const int q = qb * 128 + w * 32 + qnt * 16 + quad * 4 + reg;
      unsigned short* orow = Ob + ((size_t)bb * S_LEN + q) * D_MODEL + h * HD;
#pragma unroll
      for (int nt = 0; nt < 4; nt++)
        orow[nt * 16 + l15] = f2bf(Oacc[qnt][nt][reg]);
    }
  }
}

// ---------------- merge partials: obuf = (O0+O1)/(l0+l1) -> bf16 ----------------
__global__ __launch_bounds__(256) void merge_kernel(const unsigned short* __restrict__ Op,
                                                    const float* __restrict__ Lp,
                                                    unsigned short* __restrict__ obuf) {
  const int e = (blockIdx.x * 256 + threadIdx.x) * 8;
  const int row = e >> 10, h = (e & 1023) >> 6;
  const float l = Lp[(size_t)row * NH + h] + Lp[(size_t)ROWS * NH + (size_t)row * NH + h];
  const float rinv = 1.0f / l;
  short8 a = *(const short8*)(Op + e);
  short8 b = *(const short8*)(Op + (size_t)ROWS * D_MODEL + e);
  unsigned t[4];
#pragma unroll
  for (int i = 0; i < 4; i++) {
    const float v0 = (bf2f((unsigned short)a[2 * i]) + bf2f((unsigned short)b[2 * i])) * rinv;
    const float v1 = (bf2f((unsigned short)a[2 * i + 1]) + bf2f((unsigned short)b[2 * i + 1])) * rinv;
    t[i] = pack_bf16(v0, v1);
  }
  *(short8*)(obuf + e) = *(short8*)t;
}

extern "C" void kernel_launch(void* const* d_in, const int* in_sizes, int n_in,
                              void* d_out, int out_size, void* d_ws, size_t ws_size,
                              hipStream_t stream) {
  const float* query = (const float*)d_in[0];
  const float* key   = (const float*)d_in[1];
  const float* value = (const float*)d_in[2];
  const float* Wq = (const float*)d_in[3];
  const float* bq = (const float*)d_in[4];
  const float* Wk = (const float*)d_in[5];
  const float* bk = (const float*)d_in[6];
  const float* Wv = (const float*)d_in[7];
  const float* bv = (const float*)d_in[8];
  const float* Wo = (const float*)d_in[9];
  const float* bo = (const float*)d_in[10];
  float* out = (float*)d_out;

  char* ws = (char*)d_ws;
  const size_t MB = 1024 * 1024;
  unsigned short* xq16 = (unsigned short*)(ws + 0 * MB);
  unsigned short* xk16 = (unsigned short*)(ws + 8 * MB);
  unsigned short* xv16 = (unsigned short*)(ws + 16 * MB);
  unsigned short* wq16 = (unsigned short*)(ws + 24 * MB);
  unsigned short* wk16 = (unsigned short*)(ws + 26 * MB);
  unsigned short* wv16 = (unsigned short*)(ws + 28 * MB);
  unsigned short* qbuf  = (unsigned short*)(ws + 32 * MB);
  unsigned short* kbuf  = (unsigned short*)(ws + 40 * MB);
  unsigned short* vtbuf = (unsigned short*)(ws + 48 * MB);
  unsigned short* wo16  = (unsigned short*)(ws + 56 * MB);
  float* Lp  = (float*)(ws + 58 * MB);
  unsigned short* Op = (unsigned short*)(ws + 0 * MB);  // 2 x 8 MB bf16 partials (aliases dead x)
  unsigned short* obuf = qbuf;                          // aliases qbuf (dead after attn)

  ConvArgs ca;
  const int NX = ROWS * D_MODEL, NW = D_MODEL * D_MODEL;
  ca.s[0] = query; ca.d[0] = xq16; ca.n[0] = NX;
  ca.s[1] = key;   ca.d[1] = xk16; ca.n[1] = NX;
  ca.s[2] = value; ca.d[2] = xv16; ca.n[2] = NX;
  ca.s[3] = Wq;    ca.d[3] = wq16; ca.n[3] = NW;
  ca.s[4] = Wk;    ca.d[4] = wk16; ca.n[4] = NW;
  ca.s[5] = Wv;    ca.d[5] = wv16; ca.n[5] = NW;
  ca.s[6] = Wo;    ca.d[6] = wo16; ca.n[6] = NW;
  hipLaunchKernelGGL(convert_bf16, dim3(NX / 2048, 7), dim3(256), 0, stream, ca);

  dim3 gqkv(ROWS / 128, D_MODEL / 128, 3);  // 768 blocks
  hipLaunchKernelGGL(gemm_qkv, gqkv, dim3(256), 0, stream,
                     xq16, xk16, xv16, wq16, wk16, wv16, bq, bk, bv,
                     qbuf, kbuf, vtbuf);

  dim3 ga(S_LEN / 128, NH, BATCH * 2);      // 1024 blocks
  hipLaunchKernelGGL(attn_kernel, ga, dim3(256), 0, stream, qbuf, kbuf, vtbuf, Op, Lp);

  hipLaunchKernelGGL(merge_kernel, dim3(ROWS * D_MODEL / 2048), dim3(256), 0, stream,
                     Op, Lp, obuf);

  dim3 go(ROWS / 64, D_MODEL / 128);        // 512 blocks
  hipLaunchKernelGGL(gemm_o, go, dim3(256), 0, stream, obuf, wo16, bo, out);
}

// Round 7
// 232.308 us; speedup vs baseline: 1.0543x; 1.0543x over previous
//
#include <hip/hip_runtime.h>
#include <hip/hip_bf16.h>

// MHA: B=2, S=2048, D=1024, H=16, hd=64, fp32 in/out.
// Round 7: revert attn to round-5 (dbuf regression); gemm_qkv LDS 48->16 KB
//          (two-pass aliased V-transpose, occupancy 3->4+ blocks/CU);
//          merge fused into gemm_o A-path (merge kernel eliminated).

constexpr int D_MODEL = 1024;
constexpr int S_LEN   = 2048;
constexpr int BATCH   = 2;
constexpr int NH      = 16;
constexpr int HD      = 64;
constexpr int ROWS    = BATCH * S_LEN;  // 4096

typedef __attribute__((ext_vector_type(8))) short short8;
typedef __attribute__((ext_vector_type(4))) float float4a;

static __device__ __forceinline__ unsigned short f2bf(float f) {
  union { float f; unsigned u; } v{f};
  unsigned r = v.u + 0x7FFFu + ((v.u >> 16) & 1u);  // RNE
  return (unsigned short)(r >> 16);
}

static __device__ __forceinline__ unsigned pack_bf16(float a, float b) {
#if __has_builtin(__builtin_amdgcn_cvt_pk_bf16_f32)
  typedef __attribute__((ext_vector_type(2))) __bf16 bf16x2;
  union { bf16x2 v; unsigned u; } c;
  c.v = __builtin_amdgcn_cvt_pk_bf16_f32(a, b);
  return c.u;
#else
  return (unsigned)f2bf(a) | ((unsigned)f2bf(b) << 16);
#endif
}

static __device__ __forceinline__ float bf2f(unsigned short u) {
  union { unsigned u; float f; } v;
  v.u = (unsigned)u << 16;
  return v.f;
}

// async 16B/lane global -> LDS
static __device__ __forceinline__ void async16(const void* g, void* l) {
  __builtin_amdgcn_global_load_lds(
      (const __attribute__((address_space(1))) unsigned int*)g,
      (__attribute__((address_space(3))) unsigned int*)l, 16, 0, 0);
}

// ---------------- fp32 -> bf16 convert ----------------
struct ConvArgs { const float* s[7]; unsigned short* d[7]; int n[7]; };

__global__ __launch_bounds__(256) void convert_bf16(ConvArgs a) {
  const int which = blockIdx.y;
  const int i = (blockIdx.x * 256 + threadIdx.x) * 8;
  if (i >= a.n[which]) return;
  const float4* s = (const float4*)(a.s[which] + i);
  float4 x = s[0], y = s[1];
  unsigned t[4] = {pack_bf16(x.x, x.y), pack_bf16(x.z, x.w),
                   pack_bf16(y.x, y.y), pack_bf16(y.z, y.w)};
  *(short8*)(a.d[which] + i) = *(short8*)t;
}

// ---------------- MFMA bf16 GEMM: Y = A @ W^T (+bias) ----------------
// 128x128 block tile, BK=32, single-buffer DMA staging (16 KB LDS).
// LDS slot swizzle: slot(r,c) = r*4 + ((c + (r>>1)) & 3)  (16B chunks).
// MODE 0: bf16 head-major [B,H,S,64], value = (acc + bias)*scale
// MODE 2: bf16 V^T [B,H,64,S] (two-pass per-wave LDS transpose, Tb aliased)
template <int MODE>
static __device__ __forceinline__ void gemm_body(
    const unsigned short* __restrict__ A, const unsigned short* __restrict__ W,
    const float* __restrict__ bias, void* __restrict__ Yv, float scale,
    unsigned short* As, unsigned short* Bs, unsigned short* Tb) {
  const int tid = threadIdx.x;
  const int w = tid >> 6, lane = tid & 63;
  const int l15 = lane & 15, quad = lane >> 4;
  const int row0 = blockIdx.x * 128, col0 = blockIdx.y * 128;
  const int wm = (w & 1) * 64, wn = (w >> 1) * 64;

  float4a acc[4][4];
#pragma unroll
  for (int i = 0; i < 4; i++)
#pragma unroll
    for (int j = 0; j < 4; j++) acc[i][j] = (float4a){0.f, 0.f, 0.f, 0.f};

  const int swA = (quad + (wm >> 1) + (l15 >> 1)) & 3;
  const int swB = (quad + (wn >> 1) + (l15 >> 1)) & 3;

  for (int kt = 0; kt < D_MODEL; kt += 32) {
    __syncthreads();  // prior ds_reads done before DMA overwrite
#pragma unroll
    for (int j = 0; j < 2; j++) {
      const int i = w * 2 + j;
      const int r = i * 16 + (lane >> 2);
      const int c = ((lane & 3) - (r >> 1)) & 3;
      async16(W + (size_t)(col0 + r) * D_MODEL + kt + c * 8, (char*)Bs + i * 1024);
      async16(A + (size_t)(row0 + r) * D_MODEL + kt + c * 8, (char*)As + i * 1024);
    }
    __syncthreads();  // drain vmcnt -> tiles resident

    short8 af[4], bf[4];
#pragma unroll
    for (int mt = 0; mt < 4; mt++) {
      const int r = wm + mt * 16 + l15;
      af[mt] = *(const short8*)&As[(r * 4 + swA) * 8];
    }
#pragma unroll
    for (int nt = 0; nt < 4; nt++) {
      const int r = wn + nt * 16 + l15;
      bf[nt] = *(const short8*)&Bs[(r * 4 + swB) * 8];
    }
#pragma unroll
    for (int mt = 0; mt < 4; mt++)
#pragma unroll
      for (int nt = 0; nt < 4; nt++)
        acc[mt][nt] = __builtin_amdgcn_mfma_f32_16x16x32_bf16(af[mt], bf[nt], acc[mt][nt], 0, 0, 0);
  }

  int cols[4];
  float bvs[4];
#pragma unroll
  for (int nt = 0; nt < 4; nt++) {
    cols[nt] = col0 + wn + nt * 16 + l15;
    bvs[nt]  = bias[cols[nt]] * ((MODE == 0) ? scale : 1.0f);
  }

  if constexpr (MODE == 0) {
    unsigned short* Y = (unsigned short*)Yv;
#pragma unroll
    for (int mt = 0; mt < 4; mt++)
#pragma unroll
      for (int r = 0; r < 4; r++) {
        const int m = row0 + wm + mt * 16 + quad * 4 + r;
        const int bb = m >> 11, s = m & 2047;
#pragma unroll
        for (int nt = 0; nt < 4; nt++) {
          const int h = cols[nt] >> 6, d = cols[nt] & 63;
          Y[(((size_t)(bb * NH + h)) * S_LEN + s) * HD + d] =
              f2bf(acc[mt][nt][r] * scale + bvs[nt]);
        }
      }
  } else {  // MODE 2: V^T, two-pass per-wave 64x32 transpose (Tb aliases staging)
    __syncthreads();  // all waves' K-loop LDS reads done before alias overwrite
    unsigned short* T = Tb + w * (64 * 32);  // 4 KB per wave
    unsigned short* Y = (unsigned short*)Yv;
#pragma unroll
    for (int p = 0; p < 2; p++) {
      if (p) { asm volatile("s_waitcnt lgkmcnt(0)" ::: "memory"); }  // pass-0 reads retired
#pragma unroll
      for (int mi = 0; mi < 2; mi++) {
        const int mt = 2 * p + mi;
#pragma unroll
        for (int r = 0; r < 4; r++) {
          const int sl = mi * 16 + quad * 4 + r;  // 0..31 within pass
          const int cch = sl >> 3;
#pragma unroll
          for (int nt = 0; nt < 4; nt++) {
            const int dl = nt * 16 + l15;
            const int slot = cch ^ (dl & 3);
            T[dl * 32 + slot * 8 + (sl & 7)] = f2bf(acc[mt][nt][r] + bvs[nt]);
          }
        }
      }
      asm volatile("s_waitcnt lgkmcnt(0)" ::: "memory");  // per-wave write->read
#pragma unroll
      for (int j = 0; j < 4; j++) {
        const int cid = j * 64 + lane;
        const int dl = cid >> 2;   // 0..63
        const int c  = cid & 3;    // s-chunk within pass
        const int slot = c ^ (dl & 3);
        short8 v = *(const short8*)&T[dl * 32 + slot * 8];
        const int col = col0 + wn + dl;
        const int h = col >> 6, d = col & 63;
        const int m = row0 + wm + p * 32 + c * 8;
        const int bb = m >> 11, s = m & 2047;
        *(short8*)&Y[(((size_t)(bb * NH + h)) * HD + d) * S_LEN + s] = v;
      }
    }
  }
}

__global__ __launch_bounds__(256) void gemm_qkv(
    const unsigned short* xq, const unsigned short* xk, const unsigned short* xv,
    const unsigned short* wq, const unsigned short* wk, const unsigned short* wv,
    const float* bq, const float* bk, const float* bv,
    unsigned short* Q, unsigned short* K, unsigned short* Vt) {
  __shared__ unsigned short smem[2 * 128 * 32];  // 16 KB: As + Bs; Tb aliases all
  unsigned short* As = smem;
  unsigned short* Bs = smem + 128 * 32;
  unsigned short* Tb = smem;
  const int z = blockIdx.z;
  // Q scale: 1/sqrt(64) * log2(e)  (softmax in exp2 domain)
  if (z == 0)      gemm_body<0>(xq, wq, bq, Q,  0.125f * 1.44269504f, As, Bs, Tb);
  else if (z == 1) gemm_body<0>(xk, wk, bk, K,  1.0f, As, Bs, Tb);
  else             gemm_body<2>(xv, wv, bv, Vt, 1.0f, As, Bs, Tb);
}

// ---------------- gemm_o with fused split-K merge ----------------
// out = ((O0+O1) * 1/(l0+l1)) @ Wo^T + bo.  64x128 tile, BK=32.
// A tile built in registers from bf16 partials (merge fused); W via DMA.
__global__ __launch_bounds__(256) void gemm_o(
    const unsigned short* __restrict__ Op, const float* __restrict__ Lp,
    const unsigned short* __restrict__ wo, const float* __restrict__ bo,
    float* __restrict__ out) {
  __shared__ unsigned short As[64 * 32];    // 4 KB
  __shared__ unsigned short Bs[128 * 32];   // 8 KB
  const int tid = threadIdx.x;
  const int w = tid >> 6, lane = tid & 63;
  const int l15 = lane & 15, quad = lane >> 4;
  const int row0 = blockIdx.x * 64, col0 = blockIdx.y * 128;
  const int wn = w * 32;

  // A-merge path: lane owns row ar, global k-chunk cg (8 bf16)
  const int ar = w * 16 + (lane >> 2);
  const int cg = lane & 3;
  const int asl = (cg + (ar >> 1)) & 3;  // LDS slot (same swizzle as DMA layout)
  const int grow = row0 + ar;
  const unsigned short* P0 = Op + (size_t)grow * D_MODEL + cg * 8;
  const unsigned short* P1 = P0 + (size_t)ROWS * D_MODEL;
  const float* L0 = Lp + (size_t)grow * NH;
  const float* L1 = L0 + (size_t)ROWS * NH;

  float4a acc[4][2];
#pragma unroll
  for (int i = 0; i < 4; i++)
#pragma unroll
    for (int j = 0; j < 2; j++) acc[i][j] = (float4a){0.f, 0.f, 0.f, 0.f};

  const int swA = (quad + (l15 >> 1)) & 3;
  const int swB = (quad + (wn >> 1) + (l15 >> 1)) & 3;

  for (int kt = 0; kt < D_MODEL; kt += 32) {
    const int h = kt >> 6;
    const float rinv = 1.0f / (L0[h] + L1[h]);
    short8 a = *(const short8*)(P0 + kt);
    short8 b = *(const short8*)(P1 + kt);
    unsigned t[4];
#pragma unroll
    for (int i = 0; i < 4; i++) {
      const float v0 = (bf2f((unsigned short)a[2 * i]) + bf2f((unsigned short)b[2 * i])) * rinv;
      const float v1 = (bf2f((unsigned short)a[2 * i + 1]) + bf2f((unsigned short)b[2 * i + 1])) * rinv;
      t[i] = pack_bf16(v0, v1);
    }
    __syncthreads();  // prior frag reads done before overwrite
    *(short8*)&As[(ar * 4 + asl) * 8] = *(short8*)t;
#pragma unroll
    for (int j = 0; j < 2; j++) {
      const int i = w * 2 + j;
      const int r = i * 16 + (lane >> 2);
      const int c = ((lane & 3) - (r >> 1)) & 3;
      async16(wo + (size_t)(col0 + r) * D_MODEL + kt + c * 8, (char*)Bs + i * 1024);
    }
    __syncthreads();  // drain vmcnt (DMA) + lgkm (ds_write)

    short8 af[4], bf[2];
#pragma unroll
    for (int mt = 0; mt < 4; mt++) {
      const int r = mt * 16 + l15;
      af[mt] = *(const short8*)&As[(r * 4 + swA) * 8];
    }
#pragma unroll
    for (int nt = 0; nt < 2; nt++) {
      const int r = wn + nt * 16 + l15;
      bf[nt] = *(const short8*)&Bs[(r * 4 + swB) * 8];
    }
#pragma unroll
    for (int mt = 0; mt < 4; mt++)
#pragma unroll
      for (int nt = 0; nt < 2; nt++)
        acc[mt][nt] = __builtin_amdgcn_mfma_f32_16x16x32_bf16(af[mt], bf[nt], acc[mt][nt], 0, 0, 0);
  }

#pragma unroll
  for (int nt = 0; nt < 2; nt++) {
    const int col = col0 + wn + nt * 16 + l15;
    const float bv = bo[col];
#pragma unroll
    for (int mt = 0; mt < 4; mt++)
#pragma unroll
      for (int r = 0; r < 4; r++) {
        const int m = row0 + mt * 16 + quad * 4 + r;
        out[(size_t)m * D_MODEL + col] = acc[mt][nt][r] + bv;
      }
  }
}

// ---------------- Flash attention, split-K x2 (round-5 verified) ----------------
__global__ __launch_bounds__(256) void attn_kernel(
    const unsigned short* __restrict__ Qh, const unsigned short* __restrict__ Kh,
    const unsigned short* __restrict__ Vt, unsigned short* __restrict__ Op,
    float* __restrict__ Lp) {
  const int qb = blockIdx.x;
  const int h  = blockIdx.y;
  const int bb = blockIdx.z >> 1, sp = blockIdx.z & 1;
  const int tid = threadIdx.x;
  const int w = tid >> 6, lane = tid & 63;
  const int l15 = lane & 15, quad = lane >> 4;

  __shared__ unsigned short Ks[64 * 64];   // slot(r,c)=r*8+((c+r)&7), 16B chunks
  __shared__ unsigned short Vs[64 * 64];
  __shared__ unsigned short Ps[4][32][72];

  const size_t bh = (size_t)(bb * NH + h);
  const unsigned short* Qp = Qh + bh * S_LEN * HD;
  const unsigned short* Kp = Kh + bh * S_LEN * HD;
  const unsigned short* Vp = Vt + bh * (size_t)HD * S_LEN;

  short8 qf[2][2];
#pragma unroll
  for (int qnt = 0; qnt < 2; qnt++)
#pragma unroll
    for (int c = 0; c < 2; c++)
      qf[qnt][c] = *(const short8*)(Qp + (size_t)(qb * 128 + w * 32 + qnt * 16 + l15) * HD +
                                    c * 32 + quad * 8);

  unsigned short ob[8] = {0x3F80, 0x3F80, 0x3F80, 0x3F80, 0x3F80, 0x3F80, 0x3F80, 0x3F80};
  const short8 ones = *(short8*)ob;

  float4a Oacc[2][4];
#pragma unroll
  for (int a = 0; a < 2; a++)
#pragma unroll
    for (int b = 0; b < 4; b++) Oacc[a][b] = (float4a){0.f, 0.f, 0.f, 0.f};
  float4a Lacc[2] = {(float4a){0.f, 0.f, 0.f, 0.f}, (float4a){0.f, 0.f, 0.f, 0.f}};

  const int sw0 = (quad + l15) & 7;
  const int sw1 = (quad + 4 + l15) & 7;

  for (int kb = sp * 1024; kb < sp * 1024 + 1024; kb += 64) {
    __syncthreads();
#pragma unroll
    for (int j = 0; j < 2; j++) {
      const int i = w * 2 + j;
      const int r = i * 8 + (lane >> 3);
      const int c = ((lane & 7) - r) & 7;
      async16(Kp + (size_t)(kb + r) * HD + c * 8, (char*)Ks + i * 1024);
      async16(Vp + (size_t)r * S_LEN + kb + c * 8, (char*)Vs + i * 1024);
    }
    __syncthreads();

    // S^T = K·Q^T, p = exp2(s) -> P (bf16) into per-wave LDS
#pragma unroll
    for (int mt = 0; mt < 4; mt++) {
      const int rb = (mt * 16 + l15) * 8;
      short8 a0 = *(const short8*)&Ks[(rb + sw0) * 8];
      short8 a1 = *(const short8*)&Ks[(rb + sw1) * 8];
#pragma unroll
      for (int qnt = 0; qnt < 2; qnt++) {
        float4a s = (float4a){0.f, 0.f, 0.f, 0.f};
        s = __builtin_amdgcn_mfma_f32_16x16x32_bf16(a0, qf[qnt][0], s, 0, 0, 0);
        s = __builtin_amdgcn_mfma_f32_16x16x32_bf16(a1, qf[qnt][1], s, 0, 0, 0);
        uint2 pk;
        pk.x = pack_bf16(__builtin_amdgcn_exp2f(s[0]), __builtin_amdgcn_exp2f(s[1]));
        pk.y = pack_bf16(__builtin_amdgcn_exp2f(s[2]), __builtin_amdgcn_exp2f(s[3]));
        *(uint2*)&Ps[w][qnt * 16 + l15][mt * 16 + quad * 4] = pk;
      }
    }
    asm volatile("s_waitcnt lgkmcnt(0)" ::: "memory");  // P write->read, same wave

    // O += P·V ; l += P·1 (MFMA)
#pragma unroll
    for (int c = 0; c < 2; c++) {
      short8 pa0 = *(const short8*)&Ps[w][l15][c * 32 + quad * 8];
      short8 pa1 = *(const short8*)&Ps[w][16 + l15][c * 32 + quad * 8];
      Lacc[0] = __builtin_amdgcn_mfma_f32_16x16x32_bf16(pa0, ones, Lacc[0], 0, 0, 0);
      Lacc[1] = __builtin_amdgcn_mfma_f32_16x16x32_bf16(pa1, ones, Lacc[1], 0, 0, 0);
      const int vsw = (c * 4 + quad + l15) & 7;
#pragma unroll
      for (int nt = 0; nt < 4; nt++) {
        short8 vb = *(const short8*)&Vs[((nt * 16 + l15) * 8 + vsw) * 8];
        Oacc[0][nt] = __builtin_amdgcn_mfma_f32_16x16x32_bf16(pa0, vb, Oacc[0][nt], 0, 0, 0);
        Oacc[1][nt] = __builtin_amdgcn_mfma_f32_16x16x32_bf16(pa1, vb, Oacc[1][nt], 0, 0, 0);
      }
    }
  }

  if (l15 == 0) {
#pragma unroll
    for (int qnt = 0; qnt < 2; qnt++)
#pragma unroll
      for (int reg = 0; reg < 4; reg++) {
        const int q = qb * 128 + w * 32 + qnt * 16 + quad * 4 + reg;
        Lp[(size_t)sp * ROWS * NH + ((size_t)bb * S_LEN + q) * NH + h] = Lacc[qnt][reg];
      }
  }

  unsigned short* Ob = Op + (size_t)sp * ROWS * D_MODEL;
#pragma unroll
  for (int qnt = 0; qnt < 2; qnt++) {
#pragma unroll
    for (int reg = 0; reg < 4; reg++) {
      const int q = qb * 128 + w * 32 + qnt * 16 + quad * 4 + reg;
      unsigned short* orow = Ob + ((size_t)bb * S_LEN + q) * D_MODEL + h * HD;
#pragma unroll
      for (int nt = 0; nt < 4; nt++)
        orow[nt * 16 + l15] = f2bf(Oacc[qnt][nt][reg]);
    }
  }
}

extern "C" void kernel_launch(void* const* d_in, const int* in_sizes, int n_in,
                              void* d_out, int out_size, void* d_ws, size_t ws_size,
                              hipStream_t stream) {
  const float* query = (const float*)d_in[0];
  const float* key   = (const float*)d_in[1];
  const float* value = (const float*)d_in[2];
  const float* Wq = (const float*)d_in[3];
  const float* bq = (const float*)d_in[4];
  const float* Wk = (const float*)d_in[5];
  const float* bk = (const float*)d_in[6];
  const float* Wv = (const float*)d_in[7];
  const float* bv = (const float*)d_in[8];
  const float* Wo = (const float*)d_in[9];
  const float* bo = (const float*)d_in[10];
  float* out = (float*)d_out;

  char* ws = (char*)d_ws;
  const size_t MB = 1024 * 1024;
  unsigned short* xq16 = (unsigned short*)(ws + 0 * MB);
  unsigned short* xk16 = (unsigned short*)(ws + 8 * MB);
  unsigned short* xv16 = (unsigned short*)(ws + 16 * MB);
  unsigned short* wq16 = (unsigned short*)(ws + 24 * MB);
  unsigned short* wk16 = (unsigned short*)(ws + 26 * MB);
  unsigned short* wv16 = (unsigned short*)(ws + 28 * MB);
  unsigned short* qbuf  = (unsigned short*)(ws + 32 * MB);
  unsigned short* kbuf  = (unsigned short*)(ws + 40 * MB);
  unsigned short* vtbuf = (unsigned short*)(ws + 48 * MB);
  unsigned short* wo16  = (unsigned short*)(ws + 56 * MB);
  float* Lp = (float*)(ws + 58 * MB);
  unsigned short* Op = (unsigned short*)(ws + 0 * MB);  // 2 x 8 MB bf16 partials (aliases dead x)

  ConvArgs ca;
  const int NX = ROWS * D_MODEL, NW = D_MODEL * D_MODEL;
  ca.s[0] = query; ca.d[0] = xq16; ca.n[0] = NX;
  ca.s[1] = key;   ca.d[1] = xk16; ca.n[1] = NX;
  ca.s[2] = value; ca.d[2] = xv16; ca.n[2] = NX;
  ca.s[3] = Wq;    ca.d[3] = wq16; ca.n[3] = NW;
  ca.s[4] = Wk;    ca.d[4] = wk16; ca.n[4] = NW;
  ca.s[5] = Wv;    ca.d[5] = wv16; ca.n[5] = NW;
  ca.s[6] = Wo;    ca.d[6] = wo16; ca.n[6] = NW;
  hipLaunchKernelGGL(convert_bf16, dim3(NX / 2048, 7), dim3(256), 0, stream, ca);

  dim3 gqkv(ROWS / 128, D_MODEL / 128, 3);  // 768 blocks
  hipLaunchKernelGGL(gemm_qkv, gqkv, dim3(256), 0, stream,
                     xq16, xk16, xv16, wq16, wk16, wv16, bq, bk, bv,
                     qbuf, kbuf, vtbuf);

  dim3 ga(S_LEN / 128, NH, BATCH * 2);      // 1024 blocks
  hipLaunchKernelGGL(attn_kernel, ga, dim3(256), 0, stream, qbuf, kbuf, vtbuf, Op, Lp);

  dim3 go(ROWS / 64, D_MODEL / 128);        // 512 blocks
  hipLaunchKernelGGL(gemm_o, go, dim3(256), 0, stream, Op, Lp, wo16, bo, out);
}